// Round 1
// baseline (7436.535 us; speedup 1.0000x reference)
//
#include <hip/hip_runtime.h>
#include <stdint.h>

typedef _Float16 half_t;
typedef _Float16 half2_t __attribute__((ext_vector_type(2)));

#define TSEQ 2048
#define NB   32
#define HD   256
#define G4   1024
#define HN_ELEMS ((size_t)TSEQ*NB*HD)

static __device__ __forceinline__ float fdot2u(uint32_t a, uint32_t b, float acc) {
  return __builtin_amdgcn_fdot2(__builtin_bit_cast(half2_t, a),
                                __builtin_bit_cast(half2_t, b), acc, false);
}
static __device__ __forceinline__ float sigm_f(float x) {
  return __builtin_amdgcn_rcpf(1.0f + __expf(-x));
}
static __device__ __forceinline__ float tanh_f(float x) {
  return 2.0f * __builtin_amdgcn_rcpf(1.0f + __expf(-2.0f * x)) - 1.0f;
}

// ---------------------------------------------------------------------------
// Prep: fold zx into W, zh into U, cast to f16 in a [kc][col][8] packed layout
// (so later register loads are coalesced); bias = bW+bU; zero h/c state.
// ---------------------------------------------------------------------------
__global__ void prep_kernel(const float* __restrict__ W, const float* __restrict__ U,
                            const float* __restrict__ bW, const float* __restrict__ bU,
                            const float* __restrict__ zx, const float* __restrict__ zh,
                            half_t* __restrict__ Wpk, half_t* __restrict__ Upk,
                            float* __restrict__ bias,
                            half_t* __restrict__ hstate, float* __restrict__ cstate) {
  int tid = blockIdx.x * 256 + threadIdx.x;   // 0..32767 over (kcG 0..31, n 0..1023)
  int n   = tid & 1023;
  int kcG = tid >> 10;
  #pragma unroll
  for (int e = 0; e < 8; ++e) {
    int k = kcG * 8 + e;
    Wpk[((size_t)kcG * 1024 + n) * 8 + e] = (half_t)(W[n * 256 + k] * zx[k]);
    Upk[((size_t)kcG * 1024 + n) * 8 + e] = (half_t)(U[n * 256 + k] * zh[k]);
  }
  if (kcG == 0) bias[n] = bW[n] + bU[n];
  if (tid < NB * HD) { hstate[tid] = (half_t)0.0f; cstate[tid] = 0.0f; }
}

// ---------------------------------------------------------------------------
// Input GEMM (chunk): gx[mloc][col] = f16( input_row . W''_col ), fp32 accum.
// W'' columns live in registers (2 cols x full K = 256 VGPRs); A rows staged
// in LDS as f16 and read via wave-uniform broadcast ds_read_b128.
// ---------------------------------------------------------------------------
__global__ __launch_bounds__(512, 2)
void gemm_kernel(const float* __restrict__ input, const half_t* __restrict__ Wpk,
                 half_t* __restrict__ gx, int row0) {
  __shared__ __align__(16) uint32_t As[32 * 128];   // 32 rows x 256 halfs
  const int tid  = threadIdx.x;
  const int mloc = blockIdx.x * 32;

  uint32_t wreg[2][128];
  #pragma unroll
  for (int c = 0; c < 2; ++c) {
    const int col = tid + c * 512;
    #pragma unroll
    for (int kc = 0; kc < 32; ++kc) {
      uint4 q = ((const uint4*)Wpk)[(size_t)kc * 1024 + col];
      wreg[c][kc * 4 + 0] = q.x; wreg[c][kc * 4 + 1] = q.y;
      wreg[c][kc * 4 + 2] = q.z; wreg[c][kc * 4 + 3] = q.w;
    }
  }
  // stage 32 rows of input (fp32 -> f16)
  #pragma unroll
  for (int i = 0; i < 4; ++i) {
    int lin = tid + i * 512;
    int row = lin >> 6, f4 = lin & 63;
    float4 v = ((const float4*)input)[((size_t)(row0 + mloc + row)) * 64 + f4];
    half2_t p0; p0[0] = (half_t)v.x; p0[1] = (half_t)v.y;
    half2_t p1; p1[0] = (half_t)v.z; p1[1] = (half_t)v.w;
    ((uint2*)As)[row * 64 + f4] = make_uint2(__builtin_bit_cast(uint32_t, p0),
                                             __builtin_bit_cast(uint32_t, p1));
  }
  __syncthreads();

  #pragma unroll 1
  for (int r = 0; r < 32; ++r) {
    const uint4* arow = (const uint4*)(As + r * 128);
    float a0 = 0.f, a1 = 0.f;
    #pragma unroll
    for (int kc = 0; kc < 32; ++kc) {
      uint4 hv = arow[kc];
      a0 = fdot2u(wreg[0][kc * 4 + 0], hv.x, a0);
      a0 = fdot2u(wreg[0][kc * 4 + 1], hv.y, a0);
      a0 = fdot2u(wreg[0][kc * 4 + 2], hv.z, a0);
      a0 = fdot2u(wreg[0][kc * 4 + 3], hv.w, a0);
      a1 = fdot2u(wreg[1][kc * 4 + 0], hv.x, a1);
      a1 = fdot2u(wreg[1][kc * 4 + 1], hv.y, a1);
      a1 = fdot2u(wreg[1][kc * 4 + 2], hv.z, a1);
      a1 = fdot2u(wreg[1][kc * 4 + 3], hv.w, a1);
    }
    size_t orow = (size_t)(mloc + r) * G4;
    gx[orow + tid]       = (half_t)a0;
    gx[orow + tid + 512] = (half_t)a1;
  }
}

// ---------------------------------------------------------------------------
// Recurrent kernel: 1 block = 1 batch row = 1 CU (84KB dyn LDS forces
// exclusivity). 512 threads = (kg in {0,1} K-half) x (j in [0,256) h-column).
// Thread (kg,j) holds U'' for gate cols {j, j+256, j+512, j+768}, K-half kg,
// in 256 VGPRs. Per step: broadcast-read h (f16, LDS), 256 x v_dot2_f32_f16,
// LDS partial reduce, thread j does all 4 gates -> c,h update locally.
// ---------------------------------------------------------------------------
__global__ __launch_bounds__(512, 2)
void rec_kernel(const half_t* __restrict__ gx, const half_t* __restrict__ Upk,
                const float* __restrict__ bias,
                half_t* __restrict__ hstate, float* __restrict__ cstate,
                float* __restrict__ out, int tbase, int TB, int last) {
  extern __shared__ __align__(16) char smem[];
  half_t* hbuf = (half_t*)smem;              // 256 f16
  float*  part = (float*)(smem + 512);       // 256*5 fp32 (stride 5: no bank clash)

  const int b   = blockIdx.x;
  const int tid = threadIdx.x;
  const int kg  = tid >> 8;
  const int j   = tid & 255;

  uint32_t ureg[4][64];                      // 4 cols x 128 k (f16 pairs)
  #pragma unroll
  for (int c = 0; c < 4; ++c) {
    const int col = j + c * 256;
    #pragma unroll
    for (int kc = 0; kc < 16; ++kc) {
      uint4 q = ((const uint4*)Upk)[(size_t)(kg * 16 + kc) * 1024 + col];
      ureg[c][kc * 4 + 0] = q.x; ureg[c][kc * 4 + 1] = q.y;
      ureg[c][kc * 4 + 2] = q.z; ureg[c][kc * 4 + 3] = q.w;
    }
  }

  float b0 = 0.f, b1 = 0.f, b2 = 0.f, b3 = 0.f, cc = 0.f;
  half_t g0 = (half_t)0.f, g1 = g0, g2 = g0, g3 = g0;
  half_t n0 = g0, n1 = g0, n2 = g0, n3 = g0;
  if (kg == 0) {
    b0 = bias[j]; b1 = bias[j + 256]; b2 = bias[j + 512]; b3 = bias[j + 768];
    cc = cstate[b * HD + j];
    hbuf[j] = hstate[b * HD + j];
    const half_t* grow = gx + (size_t)b * G4;      // t=0 row
    g0 = grow[j]; g1 = grow[j + 256]; g2 = grow[j + 512]; g3 = grow[j + 768];
  }
  __syncthreads();

  float hlastf = 0.f;
  #pragma unroll 1
  for (int t = 0; t < TB; ++t) {
    // prefetch next step's x-gates (hidden under the dot phase)
    if (kg == 0 && t + 1 < TB) {
      const half_t* grow = gx + ((size_t)(t + 1) * NB + b) * G4;
      n0 = grow[j]; n1 = grow[j + 256]; n2 = grow[j + 512]; n3 = grow[j + 768];
    }
    float a0 = 0.f, a1 = 0.f, a2 = 0.f, a3 = 0.f;
    const uint4* hp = ((const uint4*)hbuf) + kg * 16;
    #pragma unroll
    for (int kc = 0; kc < 16; ++kc) {
      uint4 hv = hp[kc];
      a0 = fdot2u(ureg[0][kc * 4 + 0], hv.x, a0);
      a0 = fdot2u(ureg[0][kc * 4 + 1], hv.y, a0);
      a0 = fdot2u(ureg[0][kc * 4 + 2], hv.z, a0);
      a0 = fdot2u(ureg[0][kc * 4 + 3], hv.w, a0);
      a1 = fdot2u(ureg[1][kc * 4 + 0], hv.x, a1);
      a1 = fdot2u(ureg[1][kc * 4 + 1], hv.y, a1);
      a1 = fdot2u(ureg[1][kc * 4 + 2], hv.z, a1);
      a1 = fdot2u(ureg[1][kc * 4 + 3], hv.w, a1);
      a2 = fdot2u(ureg[2][kc * 4 + 0], hv.x, a2);
      a2 = fdot2u(ureg[2][kc * 4 + 1], hv.y, a2);
      a2 = fdot2u(ureg[2][kc * 4 + 2], hv.z, a2);
      a2 = fdot2u(ureg[2][kc * 4 + 3], hv.w, a2);
      a3 = fdot2u(ureg[3][kc * 4 + 0], hv.x, a3);
      a3 = fdot2u(ureg[3][kc * 4 + 1], hv.y, a3);
      a3 = fdot2u(ureg[3][kc * 4 + 2], hv.z, a3);
      a3 = fdot2u(ureg[3][kc * 4 + 3], hv.w, a3);
    }
    if (kg == 1) {
      part[j * 5 + 0] = a0; part[j * 5 + 1] = a1;
      part[j * 5 + 2] = a2; part[j * 5 + 3] = a3;
    }
    __syncthreads();
    if (kg == 0) {
      a0 += part[j * 5 + 0] + b0 + (float)g0;
      a1 += part[j * 5 + 1] + b1 + (float)g1;
      a2 += part[j * 5 + 2] + b2 + (float)g2;
      a3 += part[j * 5 + 3] + b3 + (float)g3;
      float gi = sigm_f(a0), gf = sigm_f(a1), go = sigm_f(a2), gg = tanh_f(a3);
      cc = gf * cc + gi * gg;
      float h = go * tanh_f(cc);
      hlastf = h;
      hbuf[j] = (half_t)h;
      out[((size_t)(tbase + t) * NB + b) * HD + j] = h;
      if (last && t == TB - 1) {
        out[HN_ELEMS + (size_t)b * HD + j] = h;
        out[HN_ELEMS + (size_t)NB * HD + (size_t)b * HD + j] = cc;
      }
      g0 = n0; g1 = n1; g2 = n2; g3 = n3;
    }
    __syncthreads();
  }
  if (kg == 0) {
    hstate[b * HD + j] = (half_t)hlastf;
    cstate[b * HD + j] = cc;
  }
}

// ---------------------------------------------------------------------------
extern "C" void kernel_launch(void* const* d_in, const int* in_sizes, int n_in,
                              void* d_out, int out_size, void* d_ws, size_t ws_size,
                              hipStream_t stream) {
  const float* input = (const float*)d_in[0];
  const float* zx    = (const float*)d_in[1];
  const float* zh    = (const float*)d_in[2];
  const float* W     = (const float*)d_in[3];
  const float* bW    = (const float*)d_in[4];
  const float* U     = (const float*)d_in[5];
  const float* bU    = (const float*)d_in[6];
  float* out = (float*)d_out;

  char* ws = (char*)d_ws;
  half_t* Upk    = (half_t*)(ws);                          // 512 KB
  half_t* Wpk    = (half_t*)(ws + (512 << 10));            // 512 KB
  float*  bias   = (float*) (ws + (1 << 20));              // 4 KB
  half_t* hstate = (half_t*)(ws + (1 << 20) + (4 << 10));  // 16 KB
  float*  cstate = (float*) (ws + (1 << 20) + (20 << 10)); // 32 KB
  half_t* gx     = (half_t*)(ws + (2 << 20));              // TB*32*1024*2 B

  // choose the largest time-chunk whose x-gate buffer fits the workspace
  int TB = TSEQ;
  while (TB > 32 && (size_t)(2u << 20) + (size_t)TB * NB * G4 * 2 > ws_size) TB >>= 1;

  hipFuncSetAttribute(reinterpret_cast<const void*>(rec_kernel),
                      hipFuncAttributeMaxDynamicSharedMemorySize, 86016);

  prep_kernel<<<128, 256, 0, stream>>>(W, U, bW, bU, zx, zh, Wpk, Upk, bias,
                                       hstate, cstate);

  int nch = TSEQ / TB;
  for (int c = 0; c < nch; ++c) {
    int tbase = c * TB;
    gemm_kernel<<<TB, 512, 0, stream>>>(input, Wpk, gx, tbase * NB);
    rec_kernel<<<32, 512, 86016, stream>>>(gx, Upk, bias, hstate, cstate, out,
                                           tbase, TB, (c == nch - 1) ? 1 : 0);
  }
}

// Round 2
// 3172.607 us; speedup vs baseline: 2.3440x; 2.3440x over previous
//
#include <hip/hip_runtime.h>
#include <stdint.h>

typedef _Float16 half_t;
typedef _Float16 half2_t __attribute__((ext_vector_type(2)));

#define TSEQ 2048
#define NB   32
#define HD   256
#define HN_ELEMS ((size_t)TSEQ*NB*HD)

static __device__ __forceinline__ float fdot2u(uint32_t a, uint32_t b, float acc) {
  return __builtin_amdgcn_fdot2(__builtin_bit_cast(half2_t, a),
                                __builtin_bit_cast(half2_t, b), acc, false);
}
static __device__ __forceinline__ float sigm_f(float x) {
  return __builtin_amdgcn_rcpf(1.0f + __expf(-x));
}
static __device__ __forceinline__ float tanh_f(float x) {
  return 2.0f * __builtin_amdgcn_rcpf(1.0f + __expf(-2.0f * x)) - 1.0f;
}

// ---------------------------------------------------------------------------
// Prep: fold zx into W, zh into U, cast to f16.
//  Wpk  : [kc][1024 cols][8 halfs]            (gemm register loads)
//  Upk3 : gates 0..2: [(c*2+kg)*16+kc][256 j][8 halfs]  (rec register loads)
//  Ug4  : gate 3:     [pc(32)][256 j][8 halfs]          (rec LDS tile)
// bias = bW+bU; zero h/c state.
// ---------------------------------------------------------------------------
__global__ void prep_kernel(const float* __restrict__ W, const float* __restrict__ U,
                            const float* __restrict__ bW, const float* __restrict__ bU,
                            const float* __restrict__ zx, const float* __restrict__ zh,
                            half_t* __restrict__ Wpk, half_t* __restrict__ Upk3,
                            half_t* __restrict__ Ug4, float* __restrict__ bias,
                            half_t* __restrict__ hstate, float* __restrict__ cstate) {
  int tid = blockIdx.x * 256 + threadIdx.x;   // (kcG 0..31) x (n 0..1023)
  int n   = tid & 1023;
  int kcG = tid >> 10;
  #pragma unroll
  for (int e = 0; e < 8; ++e) {
    int k = kcG * 8 + e;
    Wpk[((size_t)kcG * 1024 + n) * 8 + e] = (half_t)(W[n * 256 + k] * zx[k]);
    float uv = U[n * 256 + k] * zh[k];
    if (n < 768) {
      int c = n >> 8, j = n & 255, kgp = kcG >> 4, kc = kcG & 15;
      Upk3[(((size_t)(c * 2 + kgp) * 16 + kc) * 256 + j) * 8 + e] = (half_t)uv;
    } else {
      Ug4[((size_t)kcG * 256 + (n & 255)) * 8 + e] = (half_t)uv;
    }
  }
  if (kcG == 0) bias[n] = bW[n] + bU[n];
  if (tid < NB * HD) { hstate[tid] = (half_t)0.0f; cstate[tid] = 0.0f; }
}

// ---------------------------------------------------------------------------
// Input GEMM: 512 threads, 1 col/thread, full K=256 in 128 VGPRs (fits the
// 2-wave/SIMD 256-reg budget). 64 rows staged in LDS as f16, broadcast reads.
// Output packed per j: gx[row][j][gate] so rec loads one uint2 per thread.
// ---------------------------------------------------------------------------
__global__ __launch_bounds__(512, 1)
void gemm_kernel(const float* __restrict__ input, const uint4* __restrict__ Wpk,
                 half_t* __restrict__ gx, int row0) {
  __shared__ __align__(16) uint4 As[64 * 32];   // 64 rows x 256 halfs = 32KB
  const int tid = threadIdx.x;
  const int halfsel = blockIdx.x & 1;
  const int rbase = (blockIdx.x >> 1) * 64;     // chunk-local row base
  const int col = halfsel * 512 + tid;

  uint32_t wreg[128];
  #pragma unroll
  for (int kc = 0; kc < 32; ++kc) {
    uint4 q = Wpk[(size_t)kc * 1024 + col];
    wreg[kc * 4 + 0] = q.x; wreg[kc * 4 + 1] = q.y;
    wreg[kc * 4 + 2] = q.z; wreg[kc * 4 + 3] = q.w;
  }
  #pragma unroll
  for (int i = 0; i < 8; ++i) {
    int lin = tid + i * 512;
    int row = lin >> 6, f4 = lin & 63;
    float4 v = ((const float4*)input)[((size_t)(row0 + rbase + row)) * 64 + f4];
    half2_t p0; p0[0] = (half_t)v.x; p0[1] = (half_t)v.y;
    half2_t p1; p1[0] = (half_t)v.z; p1[1] = (half_t)v.w;
    ((uint2*)As)[row * 64 + f4] = make_uint2(__builtin_bit_cast(uint32_t, p0),
                                             __builtin_bit_cast(uint32_t, p1));
  }
  __syncthreads();

  const int gate = col >> 8, j = col & 255;
  #pragma unroll 1
  for (int r = 0; r < 64; ++r) {
    const uint4* arow = As + r * 32;
    float a0 = 0.f, a1 = 0.f;
    #pragma unroll
    for (int kc = 0; kc < 16; ++kc) {
      uint4 h0 = arow[2 * kc], h1 = arow[2 * kc + 1];
      a0 = fdot2u(wreg[8 * kc + 0], h0.x, a0);
      a0 = fdot2u(wreg[8 * kc + 1], h0.y, a0);
      a0 = fdot2u(wreg[8 * kc + 2], h0.z, a0);
      a0 = fdot2u(wreg[8 * kc + 3], h0.w, a0);
      a1 = fdot2u(wreg[8 * kc + 4], h1.x, a1);
      a1 = fdot2u(wreg[8 * kc + 5], h1.y, a1);
      a1 = fdot2u(wreg[8 * kc + 6], h1.z, a1);
      a1 = fdot2u(wreg[8 * kc + 7], h1.w, a1);
    }
    gx[((size_t)(rbase + r) * HD + j) * 4 + gate] = (half_t)(a0 + a1);
  }
}

// ---------------------------------------------------------------------------
// Recurrent kernel: 1 block = 1 batch chain = 1 CU (133.5KB LDS -> exclusive).
// 512 threads = (kg K-half) x (j h-column). Register demand made feasible:
// gates i,f,o U in 192 VGPRs/thread; gate g U in a 128KB LDS tile read via
// conflict-free consecutive-lane ds_read_b128. h broadcast from LDS.
// ---------------------------------------------------------------------------
__global__ __launch_bounds__(512, 1)
void rec_kernel(const half_t* __restrict__ gx, const uint4* __restrict__ Upk3,
                const uint4* __restrict__ Ug4, const float* __restrict__ bias,
                half_t* __restrict__ hstate, float* __restrict__ cstate,
                float* __restrict__ out, int tbase, int TB, int last) {
  extern __shared__ __align__(16) char smem[];
  uint4*  uglds = (uint4*)smem;                    // 8192 uint4 = 128KB
  half_t* hbuf  = (half_t*)(smem + 131072);        // 256 f16
  float*  part  = (float*)(smem + 131072 + 512);   // 256*5 f32 (stride 5)

  const int b   = blockIdx.x;
  const int tid = threadIdx.x;
  const int kg  = tid >> 8;
  const int j   = tid & 255;

  // stage gate-g U into LDS (one-time, coalesced, linear)
  #pragma unroll
  for (int i = 0; i < 16; ++i) uglds[i * 512 + tid] = Ug4[i * 512 + tid];

  uint32_t ureg[3][64];                            // gates i,f,o: 192 VGPRs
  #pragma unroll
  for (int c = 0; c < 3; ++c) {
    #pragma unroll
    for (int kc = 0; kc < 16; ++kc) {
      uint4 q = Upk3[((size_t)(c * 2 + kg) * 16 + kc) * 256 + j];
      ureg[c][kc * 4 + 0] = q.x; ureg[c][kc * 4 + 1] = q.y;
      ureg[c][kc * 4 + 2] = q.z; ureg[c][kc * 4 + 3] = q.w;
    }
  }

  const uint2* gx2 = (const uint2*)gx;
  float b0 = 0.f, b1 = 0.f, b2 = 0.f, b3 = 0.f, cc = 0.f;
  uint2 gpk = make_uint2(0, 0), npk = make_uint2(0, 0);
  if (kg == 0) {
    b0 = bias[j]; b1 = bias[j + 256]; b2 = bias[j + 512]; b3 = bias[j + 768];
    cc = cstate[b * HD + j];
    hbuf[j] = hstate[b * HD + j];
    gpk = gx2[(size_t)b * HD + j];                 // t=0 row (chunk-local)
  }
  __syncthreads();

  float hlastf = 0.f;
  #pragma unroll 1
  for (int t = 0; t < TB; ++t) {
    if (kg == 0 && t + 1 < TB)
      npk = gx2[((size_t)(t + 1) * NB + b) * HD + j];   // prefetch next x-gates

    float a0 = 0.f, a1 = 0.f, a2 = 0.f, a3 = 0.f;
    const uint4* hp  = (const uint4*)hbuf + kg * 16;
    const uint4* ugp = uglds + (size_t)kg * 16 * 256 + j;
    #pragma unroll
    for (int kc = 0; kc < 16; ++kc) {
      uint4 hv = hp[kc];
      uint4 ug = ugp[kc * 256];
      a0 = fdot2u(ureg[0][kc * 4 + 0], hv.x, a0);
      a0 = fdot2u(ureg[0][kc * 4 + 1], hv.y, a0);
      a0 = fdot2u(ureg[0][kc * 4 + 2], hv.z, a0);
      a0 = fdot2u(ureg[0][kc * 4 + 3], hv.w, a0);
      a1 = fdot2u(ureg[1][kc * 4 + 0], hv.x, a1);
      a1 = fdot2u(ureg[1][kc * 4 + 1], hv.y, a1);
      a1 = fdot2u(ureg[1][kc * 4 + 2], hv.z, a1);
      a1 = fdot2u(ureg[1][kc * 4 + 3], hv.w, a1);
      a2 = fdot2u(ureg[2][kc * 4 + 0], hv.x, a2);
      a2 = fdot2u(ureg[2][kc * 4 + 1], hv.y, a2);
      a2 = fdot2u(ureg[2][kc * 4 + 2], hv.z, a2);
      a2 = fdot2u(ureg[2][kc * 4 + 3], hv.w, a2);
      a3 = fdot2u(ug.x, hv.x, a3);
      a3 = fdot2u(ug.y, hv.y, a3);
      a3 = fdot2u(ug.z, hv.z, a3);
      a3 = fdot2u(ug.w, hv.w, a3);
    }
    if (kg == 1) {
      part[j * 5 + 0] = a0; part[j * 5 + 1] = a1;
      part[j * 5 + 2] = a2; part[j * 5 + 3] = a3;
    }
    __syncthreads();
    if (kg == 0) {
      half2_t g01 = __builtin_bit_cast(half2_t, gpk.x);
      half2_t g23 = __builtin_bit_cast(half2_t, gpk.y);
      a0 += part[j * 5 + 0] + b0 + (float)g01[0];
      a1 += part[j * 5 + 1] + b1 + (float)g01[1];
      a2 += part[j * 5 + 2] + b2 + (float)g23[0];
      a3 += part[j * 5 + 3] + b3 + (float)g23[1];
      float gi = sigm_f(a0), gf = sigm_f(a1), go = sigm_f(a2), gg = tanh_f(a3);
      cc = gf * cc + gi * gg;
      float h = go * tanh_f(cc);
      hlastf = h;
      hbuf[j] = (half_t)h;
      out[((size_t)(tbase + t) * NB + b) * HD + j] = h;
      if (last && t == TB - 1) {
        out[HN_ELEMS + (size_t)b * HD + j] = h;
        out[HN_ELEMS + (size_t)NB * HD + (size_t)b * HD + j] = cc;
      }
      gpk = npk;
    }
    __syncthreads();
  }
  if (kg == 0) {
    hstate[b * HD + j] = (half_t)hlastf;
    cstate[b * HD + j] = cc;
  }
}

// ---------------------------------------------------------------------------
extern "C" void kernel_launch(void* const* d_in, const int* in_sizes, int n_in,
                              void* d_out, int out_size, void* d_ws, size_t ws_size,
                              hipStream_t stream) {
  const float* input = (const float*)d_in[0];
  const float* zx    = (const float*)d_in[1];
  const float* zh    = (const float*)d_in[2];
  const float* W     = (const float*)d_in[3];
  const float* bW    = (const float*)d_in[4];
  const float* U     = (const float*)d_in[5];
  const float* bU    = (const float*)d_in[6];
  float* out = (float*)d_out;

  char* ws = (char*)d_ws;
  uint4*  Upk3   = (uint4*)(ws);                           // 384 KB
  uint4*  Ug4    = (uint4*)(ws + (384 << 10));             // 128 KB
  uint4*  Wpk    = (uint4*)(ws + (512 << 10));             // 512 KB
  float*  bias   = (float*) (ws + (1 << 20));              // 4 KB
  half_t* hstate = (half_t*)(ws + (1 << 20) + (4 << 10));  // 16 KB
  float*  cstate = (float*) (ws + (1 << 20) + (20 << 10)); // 32 KB
  half_t* gx     = (half_t*)(ws + (2 << 20));              // TB*32*1024*2 B

  int TB = TSEQ;
  while (TB > 32 && (size_t)(2u << 20) + (size_t)TB * NB * 1024 * 2 > ws_size) TB >>= 1;

  hipFuncSetAttribute(reinterpret_cast<const void*>(rec_kernel),
                      hipFuncAttributeMaxDynamicSharedMemorySize, 136704);

  prep_kernel<<<128, 256, 0, stream>>>(W, U, bW, bU, zx, zh,
                                       (half_t*)Wpk, (half_t*)Upk3, (half_t*)Ug4,
                                       bias, hstate, cstate);

  int nch = TSEQ / TB;
  for (int c = 0; c < nch; ++c) {
    int tbase = c * TB;
    gemm_kernel<<<(TB * NB / 64) * 2, 512, 0, stream>>>(input, Wpk, gx, tbase * NB);
    rec_kernel<<<NB, 512, 136704, stream>>>(gx, Upk3, Ug4, bias, hstate, cstate, out,
                                            tbase, TB, (c == nch - 1) ? 1 : 0);
  }
}